// Round 1
// baseline (196.879 us; speedup 1.0000x reference)
//
#include <hip/hip_runtime.h>
#include <hip/hip_bf16.h>
#include <stdint.h>

// TT linear 4096->4096, B=2048, ranks (1,16,16,16,1), modes 8^4.
// Strategy: materialize dense W = TT-chain (cheap: ~0.3 GFLOP), then one
// bf16 MFMA BT-GEMM out = X * W^T + bias (68.7 GFLOP).

typedef __bf16 bf16_t;
typedef __bf16 bf16x8 __attribute__((ext_vector_type(8)));
typedef float floatx4 __attribute__((ext_vector_type(4)));

#define BATCH_N 2048
#define KD 4096     // inner dim (input features)
#define ND 4096     // output features

__device__ static inline void load_lds16(const void* g, void* l) {
    __builtin_amdgcn_global_load_lds(
        (const __attribute__((address_space(1))) void*)g,
        (__attribute__((address_space(3))) void*)l, 16, 0, 0);
}

// ---- x fp32 -> bf16, 8 elements/thread --------------------------------
__global__ __launch_bounds__(256) void cvt_x(const float* __restrict__ x,
                                             bf16_t* __restrict__ xb) {
    int t = blockIdx.x * 256 + threadIdx.x;     // 1,048,576 threads
    const float4* xv = (const float4*)x;
    float4 a = xv[t * 2];
    float4 b = xv[t * 2 + 1];
    bf16x8 o;
    o[0] = (bf16_t)a.x; o[1] = (bf16_t)a.y; o[2] = (bf16_t)a.z; o[3] = (bf16_t)a.w;
    o[4] = (bf16_t)b.x; o[5] = (bf16_t)b.y; o[6] = (bf16_t)b.z; o[7] = (bf16_t)b.w;
    ((bf16x8*)xb)[t] = o;
}

// ---- P[M01*1024 + N01*16 + r2] = sum_r1 core0[m0][n0*16+r1]*core1[r1*8+m1][n1*16+r2]
__global__ __launch_bounds__(256) void build_p(const float* __restrict__ c0,
                                               const float* __restrict__ c1,
                                               float* __restrict__ P) {
    int o = blockIdx.x * 256 + threadIdx.x;     // 65536
    int r2 = o & 15, N01 = (o >> 4) & 63, M01 = o >> 10;
    int m0 = M01 >> 3, m1 = M01 & 7, n0 = N01 >> 3, n1 = N01 & 7;
    float s = 0.f;
#pragma unroll
    for (int r1 = 0; r1 < 16; ++r1)
        s += c0[m0 * 128 + n0 * 16 + r1] * c1[(r1 * 8 + m1) * 128 + n1 * 16 + r2];
    P[o] = s;
}

// ---- T1[r2*4096 + M23*64 + N23] = sum_r3 core2[r2*8+m2][n2*16+r3]*core3[r3*8+m3][n3]
__global__ __launch_bounds__(256) void build_t1(const float* __restrict__ c2,
                                                const float* __restrict__ c3,
                                                float* __restrict__ T1) {
    int o = blockIdx.x * 256 + threadIdx.x;     // 65536
    int N23 = o & 63, M23 = (o >> 6) & 63, r2 = o >> 12;
    int n2 = N23 >> 3, n3 = N23 & 7, m2 = M23 >> 3, m3 = M23 & 7;
    float s = 0.f;
#pragma unroll
    for (int r3 = 0; r3 < 16; ++r3)
        s += c2[(r2 * 8 + m2) * 128 + n2 * 16 + r3] * c3[(r3 * 8 + m3) * 8 + n3];
    T1[o] = s;
}

// ---- W[j,i] (bf16, row-major [4096][4096]) = sum_r2 P[M01,N01,r2]*T1[r2,M23,N23]
// j = M01*64 + M23, i = N01*64 + N23. One block per (M23, N01): 64x16 @ 16x64.
__global__ __launch_bounds__(256) void build_w(const float* __restrict__ P,
                                               const float* __restrict__ T1,
                                               bf16_t* __restrict__ W) {
    __shared__ float Pl[64 * 16];    // [M01][r2]
    __shared__ float T1l[16 * 64];   // [r2][N23]
    int b = blockIdx.x;              // 4096 blocks
    int M23 = b >> 6, N01 = b & 63;
    int t = threadIdx.x;
    for (int i = t; i < 1024; i += 256) {
        int m01 = i >> 4, r2 = i & 15;
        Pl[i] = P[m01 * 1024 + N01 * 16 + r2];
    }
    for (int i = t; i < 1024; i += 256) {
        int r2 = i >> 6, n23 = i & 63;
        T1l[i] = T1[r2 * 4096 + M23 * 64 + n23];
    }
    __syncthreads();
    int n23 = t & 63, q = t >> 6;
#pragma unroll
    for (int g = 0; g < 16; ++g) {
        int m01 = q * 16 + g;
        float s = 0.f;
#pragma unroll
        for (int r2 = 0; r2 < 16; ++r2) s += Pl[m01 * 16 + r2] * T1l[r2 * 64 + n23];
        W[(size_t)(m01 * 64 + M23) * 4096 + N01 * 64 + n23] = (bf16_t)s;
    }
}

// ---- BT GEMM: C[m,n] = sum_k A[m,k]*B[n,k] + bias[n] ------------------
// A = Xb [2048 x 4096] bf16, B = W [4096 x 4096] bf16, C fp32.
// 128x128 tile, BK=32, 256 threads (4 waves, 2x2), 4x4 16x16x32 MFMAs/wave.
__global__ __launch_bounds__(256) void gemm_bt(const bf16_t* __restrict__ A,
                                               const bf16_t* __restrict__ B,
                                               const float* __restrict__ bias,
                                               float* __restrict__ C) {
    __shared__ bf16_t As[128 * 32];
    __shared__ bf16_t Bs[128 * 32];
    const int t = threadIdx.x;
    const int bn = blockIdx.x, bm = blockIdx.y;
    const int lane = t & 63, wave = t >> 6;
    const int wm = wave >> 1, wn = wave & 1;

    // staging map: thread t -> row t/4 (per 64-row half), k-chunk (t%3)*8
    const int sr = t >> 2;
    const int sk = (t & 3) * 8;
    const bf16_t* Agp = A + (size_t)(bm * 128 + sr) * KD + sk;
    const bf16_t* Bgp = B + (size_t)(bn * 128 + sr) * KD + sk;

    floatx4 acc[4][4];
    floatx4 zero = {0.f, 0.f, 0.f, 0.f};
#pragma unroll
    for (int i = 0; i < 4; ++i)
#pragma unroll
        for (int j = 0; j < 4; ++j) acc[i][j] = zero;

    const int fr = lane & 15;            // fragment row (m or n)
    const int fk = (lane >> 4) * 8;      // fragment k offset

    for (int k0 = 0; k0 < KD; k0 += 32) {
        __syncthreads();
#pragma unroll
        for (int h = 0; h < 2; ++h) {
            load_lds16(Agp + (size_t)(h * 64) * KD + k0, As + h * 2048 + wave * 512);
            load_lds16(Bgp + (size_t)(h * 64) * KD + k0, Bs + h * 2048 + wave * 512);
        }
        __syncthreads();

        bf16x8 af[4], bf[4];
#pragma unroll
        for (int im = 0; im < 4; ++im)
            af[im] = *(const bf16x8*)(As + (wm * 64 + im * 16 + fr) * 32 + fk);
#pragma unroll
        for (int in = 0; in < 4; ++in)
            bf[in] = *(const bf16x8*)(Bs + (wn * 64 + in * 16 + fr) * 32 + fk);
#pragma unroll
        for (int im = 0; im < 4; ++im)
#pragma unroll
            for (int in = 0; in < 4; ++in)
                acc[im][in] = __builtin_amdgcn_mfma_f32_16x16x32_bf16(
                    af[im], bf[in], acc[im][in], 0, 0, 0);
    }

    // epilogue: D[m=(lane>>4)*4+reg][n=lane&15]
    const int rl = lane >> 4, cl = lane & 15;
    const size_t rbase = (size_t)bm * 128 + wm * 64;
    const int cbase = bn * 128 + wn * 64;
#pragma unroll
    for (int im = 0; im < 4; ++im) {
#pragma unroll
        for (int in = 0; in < 4; ++in) {
            int col = cbase + in * 16 + cl;
            float bv = bias[col];
#pragma unroll
            for (int r = 0; r < 4; ++r) {
                size_t row = rbase + im * 16 + rl * 4 + r;
                C[row * ND + col] = acc[im][in][r] + bv;
            }
        }
    }
}

extern "C" void kernel_launch(void* const* d_in, const int* in_sizes, int n_in,
                              void* d_out, int out_size, void* d_ws, size_t ws_size,
                              hipStream_t stream) {
    const float* x  = (const float*)d_in[0];
    const float* c0 = (const float*)d_in[1];
    const float* c1 = (const float*)d_in[2];
    const float* c2 = (const float*)d_in[3];
    const float* c3 = (const float*)d_in[4];
    const float* bias = (const float*)d_in[5];
    float* out = (float*)d_out;

    char* ws = (char*)d_ws;
    bf16_t* Xb = (bf16_t*)ws;                               // 16 MiB
    bf16_t* W  = (bf16_t*)(ws + (16u << 20));               // 32 MiB
    float*  P  = (float*)(ws + (48u << 20));                // 256 KiB
    float*  T1 = (float*)(ws + (48u << 20) + (256u << 10)); // 256 KiB

    cvt_x<<<4096, 256, 0, stream>>>(x, Xb);
    build_p<<<256, 256, 0, stream>>>(c0, c1, P);
    build_t1<<<256, 256, 0, stream>>>(c2, c3, T1);
    build_w<<<4096, 256, 0, stream>>>(P, T1, W);
    dim3 grid(ND / 128, BATCH_N / 128);
    gemm_bt<<<grid, 256, 0, stream>>>(Xb, W, bias, out);
}